// Round 1
// baseline (138.823 us; speedup 1.0000x reference)
//
#include <hip/hip_runtime.h>

typedef _Float16 half8 __attribute__((ext_vector_type(8)));
typedef float floatx4 __attribute__((ext_vector_type(4)));

constexpr int NSEQ = 2048;
constexpr int NDIM = 512;
constexpr int DH   = 64;
constexpr float SCALE = 0.125f;  // (512/8)^-0.5

constexpr int QB = 64;           // Q rows per block (16 per wave)
constexpr int KB = 64;           // K/V rows per tile
constexpr int LDK = DH + 8;      // 72 f16 = 144 B: rows 16B-aligned, 2-way bank alias (free)
constexpr int LDV = KB + 8;
constexpr int LDP = KB + 8;

__launch_bounds__(256, 2)
__global__ void mha_fwd(const float* __restrict__ Q,
                        const float* __restrict__ K,
                        const float* __restrict__ V,
                        float* __restrict__ O)
{
    __shared__ _Float16 sK[KB * LDK];        // K tile, row-major [j][k]
    __shared__ _Float16 sVT[DH * LDV];       // V tile transposed [d][j]
    __shared__ _Float16 sP[4][16 * LDP];     // per-wave P tile [qrow][j]

    const int tid  = threadIdx.x;
    const int wave = tid >> 6;
    const int lane = tid & 63;
    const int lr   = lane & 15;   // col index within 16 / row for A-frag
    const int lg   = lane >> 4;   // k-group

    const int bid = blockIdx.x;          // (b*8 + h)*32 + qtile
    const int qt  = bid & 31;
    const int bh  = bid >> 5;
    const int h   = bh & 7;
    const int b   = bh >> 3;

    const int qrow0 = qt * QB + wave * 16;

    // ---- load Q fragments (A-layout: row=lr, k=lg*8+j (+32c)), fold in SCALE
    half8 aq[2];
    {
        const float* qp = Q + ((size_t)b * NSEQ + qrow0 + lr) * NDIM + h * DH;
        #pragma unroll
        for (int c = 0; c < 2; ++c) {
            floatx4 x0 = *(const floatx4*)(qp + c * 32 + lg * 8);
            floatx4 x1 = *(const floatx4*)(qp + c * 32 + lg * 8 + 4);
            #pragma unroll
            for (int j = 0; j < 4; ++j) {
                aq[c][j]     = (_Float16)(x0[j] * SCALE);
                aq[c][4 + j] = (_Float16)(x1[j] * SCALE);
            }
        }
    }

    floatx4 acc[4];
    float m_r[4], l_r[4];
    #pragma unroll
    for (int t = 0; t < 4; ++t) acc[t] = (floatx4){0.f, 0.f, 0.f, 0.f};
    #pragma unroll
    for (int r = 0; r < 4; ++r) { m_r[r] = -1e30f; l_r[r] = 0.f; }

    const float* kbase = K + (size_t)b * NSEQ * NDIM + h * DH;
    const float* vbase = V + (size_t)b * NSEQ * NDIM + h * DH;

    for (int kt = 0; kt < NSEQ / KB; ++kt) {
        const int n0 = kt * KB;
        __syncthreads();   // prior PV reads done before overwriting K/V tiles

        // ---- stage K tile (row-major, fp32 -> fp16)
        {
            const int j  = tid >> 2;
            const int c0 = (tid & 3) * 16;
            const float* src = kbase + (size_t)(n0 + j) * NDIM + c0;
            _Float16* dst = &sK[j * LDK + c0];
            #pragma unroll
            for (int q4 = 0; q4 < 4; ++q4) {
                floatx4 v = *(const floatx4*)(src + q4 * 4);
                dst[q4 * 4 + 0] = (_Float16)v[0];
                dst[q4 * 4 + 1] = (_Float16)v[1];
                dst[q4 * 4 + 2] = (_Float16)v[2];
                dst[q4 * 4 + 3] = (_Float16)v[3];
            }
        }
        // ---- stage V tile transposed (4x4 micro-transpose per thread)
        {
            const int jb = (tid & 15) * 4;
            const int cb = (tid >> 4) * 4;
            const float* src = vbase + (size_t)(n0 + jb) * NDIM + cb;
            floatx4 r0 = *(const floatx4*)(src);
            floatx4 r1 = *(const floatx4*)(src + NDIM);
            floatx4 r2 = *(const floatx4*)(src + 2 * NDIM);
            floatx4 r3 = *(const floatx4*)(src + 3 * NDIM);
            #pragma unroll
            for (int cc = 0; cc < 4; ++cc) {
                _Float16* dst = &sVT[(cb + cc) * LDV + jb];
                dst[0] = (_Float16)r0[cc];
                dst[1] = (_Float16)r1[cc];
                dst[2] = (_Float16)r2[cc];
                dst[3] = (_Float16)r3[cc];
            }
        }
        __syncthreads();

        // ---- S = (Q*scale) K^T   (16 x 64 per wave)
        floatx4 s[4];
        #pragma unroll
        for (int t = 0; t < 4; ++t) {
            half8 bk0 = *(const half8*)&sK[(t * 16 + lr) * LDK + lg * 8];
            half8 bk1 = *(const half8*)&sK[(t * 16 + lr) * LDK + 32 + lg * 8];
            floatx4 z = (floatx4){0.f, 0.f, 0.f, 0.f};
            z = __builtin_amdgcn_mfma_f32_16x16x32_f16(aq[0], bk0, z, 0, 0, 0);
            z = __builtin_amdgcn_mfma_f32_16x16x32_f16(aq[1], bk1, z, 0, 0, 0);
            s[t] = z;
        }

        // ---- online softmax (C/D layout: col=lr, row=lg*4+r)
        float vmax[4];
        #pragma unroll
        for (int r = 0; r < 4; ++r)
            vmax[r] = fmaxf(fmaxf(s[0][r], s[1][r]), fmaxf(s[2][r], s[3][r]));
        #pragma unroll
        for (int msk = 1; msk < 16; msk <<= 1) {
            #pragma unroll
            for (int r = 0; r < 4; ++r)
                vmax[r] = fmaxf(vmax[r], __shfl_xor(vmax[r], msk, 64));
        }
        float fr[4];
        #pragma unroll
        for (int r = 0; r < 4; ++r) {
            float mn = fmaxf(m_r[r], vmax[r]);
            fr[r] = __expf(m_r[r] - mn);
            m_r[r] = mn;
        }
        #pragma unroll
        for (int t = 0; t < 4; ++t) {
            #pragma unroll
            for (int r = 0; r < 4; ++r)
                s[t][r] = __expf(s[t][r] - m_r[r]);
        }
        float vsum[4];
        #pragma unroll
        for (int r = 0; r < 4; ++r)
            vsum[r] = (s[0][r] + s[1][r]) + (s[2][r] + s[3][r]);
        #pragma unroll
        for (int msk = 1; msk < 16; msk <<= 1) {
            #pragma unroll
            for (int r = 0; r < 4; ++r)
                vsum[r] += __shfl_xor(vsum[r], msk, 64);
        }
        #pragma unroll
        for (int r = 0; r < 4; ++r)
            l_r[r] = l_r[r] * fr[r] + vsum[r];
        #pragma unroll
        for (int t = 0; t < 4; ++t) {
            #pragma unroll
            for (int r = 0; r < 4; ++r)
                acc[t][r] *= fr[r];
        }

        // ---- P -> LDS (convert C/D layout to A layout via round-trip)
        #pragma unroll
        for (int t = 0; t < 4; ++t) {
            #pragma unroll
            for (int r = 0; r < 4; ++r)
                sP[wave][(lg * 4 + r) * LDP + t * 16 + lr] = (_Float16)s[t][r];
        }
        __syncthreads();   // also guarantees our own P writes are visible

        // ---- O += P V
        half8 ap0 = *(const half8*)&sP[wave][lr * LDP + lg * 8];
        half8 ap1 = *(const half8*)&sP[wave][lr * LDP + 32 + lg * 8];
        #pragma unroll
        for (int t = 0; t < 4; ++t) {
            half8 bv0 = *(const half8*)&sVT[(t * 16 + lr) * LDV + lg * 8];
            half8 bv1 = *(const half8*)&sVT[(t * 16 + lr) * LDV + 32 + lg * 8];
            acc[t] = __builtin_amdgcn_mfma_f32_16x16x32_f16(ap0, bv0, acc[t], 0, 0, 0);
            acc[t] = __builtin_amdgcn_mfma_f32_16x16x32_f16(ap1, bv1, acc[t], 0, 0, 0);
        }
    }

    // ---- epilogue: normalize and store
    float inv[4];
    #pragma unroll
    for (int r = 0; r < 4; ++r) inv[r] = 1.0f / l_r[r];
    #pragma unroll
    for (int t = 0; t < 4; ++t) {
        #pragma unroll
        for (int r = 0; r < 4; ++r)
            O[((size_t)b * NSEQ + qrow0 + lg * 4 + r) * NDIM + h * DH + t * 16 + lr]
                = acc[t][r] * inv[r];
    }
}

extern "C" void kernel_launch(void* const* d_in, const int* in_sizes, int n_in,
                              void* d_out, int out_size, void* d_ws, size_t ws_size,
                              hipStream_t stream) {
    const float* Q = (const float*)d_in[0];
    const float* K = (const float*)d_in[1];
    const float* V = (const float*)d_in[2];
    float* O = (float*)d_out;
    // grid = B*H*(N/QB) = 4*8*32 = 1024
    dim3 grid(4 * 8 * (NSEQ / QB));
    dim3 block(256);
    hipLaunchKernelGGL(mha_fwd, grid, block, 0, stream, Q, K, V, O);
}

// Round 2
// 102.116 us; speedup vs baseline: 1.3595x; 1.3595x over previous
//
#include <hip/hip_runtime.h>

typedef _Float16 half4 __attribute__((ext_vector_type(4)));
typedef _Float16 half8 __attribute__((ext_vector_type(8)));
typedef float floatx4 __attribute__((ext_vector_type(4)));

constexpr int NSEQ = 2048;
constexpr int NDIM = 512;
constexpr int DH   = 64;
constexpr float SCALE = 0.125f;   // (512/8)^-0.5

constexpr int QB  = 64;           // Q rows per block (16 per wave)
constexpr int KB  = 64;           // K/V rows per tile
constexpr int NT  = NSEQ / KB;    // 32 tiles
constexpr int LDK = DH + 8;       // 72 halves = 144 B rows
constexpr int LDV = KB + 8;       // 72

__launch_bounds__(256, 4)
__global__ void mha_fwd(const float* __restrict__ Q,
                        const float* __restrict__ K,
                        const float* __restrict__ V,
                        float* __restrict__ O)
{
    __shared__ _Float16 sK[2][KB * LDK];    // [buf][k_row][d]
    __shared__ _Float16 sVT[2][DH * LDV];   // [buf][d][k_row]  (V transposed)

    const int tid  = threadIdx.x;
    const int wave = tid >> 6;
    const int lane = tid & 63;
    const int lr   = lane & 15;
    const int lg   = lane >> 4;

    const int bid = blockIdx.x;          // (b*8 + h)*32 + qtile
    const int qt  = bid & 31;
    const int bh  = bid >> 5;
    const int h   = bh & 7;
    const int b   = bh >> 3;
    const int qrow0 = qt * QB + wave * 16;

    // ---- Q as B-fragments of 16x16x32 (j=q=lr, d=lg*8+[0..7], chunk c = +32), SCALE folded
    half8 aq[2];
    {
        const float* qp = Q + ((size_t)b * NSEQ + qrow0 + lr) * NDIM + h * DH;
        #pragma unroll
        for (int c = 0; c < 2; ++c) {
            floatx4 x0 = *(const floatx4*)(qp + c * 32 + lg * 8);
            floatx4 x1 = *(const floatx4*)(qp + c * 32 + lg * 8 + 4);
            #pragma unroll
            for (int j = 0; j < 4; ++j) {
                aq[c][j]     = (_Float16)(x0[j] * SCALE);
                aq[c][4 + j] = (_Float16)(x1[j] * SCALE);
            }
        }
    }

    // ---- staging assignment (256 threads)
    const int jk = tid >> 2;             // K row         (64 rows)
    const int ck = (tid & 3) * 16;       // K col base    (4 x 16 f32)
    const int jv = (tid & 15) * 4;       // V row base    (16 x 4 rows)
    const int cv = (tid >> 4) * 4;       // V col base    (16 x 4 cols)

    const float* kbase = K + (size_t)b * NSEQ * NDIM + h * DH;
    const float* vbase = V + (size_t)b * NSEQ * NDIM + h * DH;

    floatx4 rk[4], rv[4];
    auto LOAD = [&](int kt) {
        const float* ks = kbase + (size_t)(kt * KB + jk) * NDIM + ck;
        #pragma unroll
        for (int q4 = 0; q4 < 4; ++q4) rk[q4] = *(const floatx4*)(ks + q4 * 4);
        const float* vs = vbase + (size_t)(kt * KB + jv) * NDIM + cv;
        #pragma unroll
        for (int i = 0; i < 4; ++i) rv[i] = *(const floatx4*)(vs + (size_t)i * NDIM);
    };
    auto WRITE = [&](int buf) {
        #pragma unroll
        for (int q4 = 0; q4 < 4; ++q4) {
            half4 w = { (_Float16)rk[q4][0], (_Float16)rk[q4][1],
                        (_Float16)rk[q4][2], (_Float16)rk[q4][3] };
            *(half4*)&sK[buf][jk * LDK + ck + q4 * 4] = w;
        }
        #pragma unroll
        for (int cc = 0; cc < 4; ++cc) {
            half4 w = { (_Float16)rv[0][cc], (_Float16)rv[1][cc],
                        (_Float16)rv[2][cc], (_Float16)rv[3][cc] };
            *(half4*)&sVT[buf][(cv + cc) * LDV + jv] = w;
        }
    };

    floatx4 accT[4];                     // O^T tiles: row=d_local(lg*4+r), col=q(lr)
    #pragma unroll
    for (int t = 0; t < 4; ++t) accT[t] = (floatx4){0.f, 0.f, 0.f, 0.f};
    float m_run = -1e30f, l_run = 0.f;

    LOAD(0);
    #pragma unroll 2
    for (int kt = 0; kt < NT; ++kt) {
        const int buf = kt & 1;
        WRITE(buf);                       // waits on prefetched loads (vmcnt)
        if (kt + 1 < NT) LOAD(kt + 1);    // prefetch next tile; latency hides under compute
        __syncthreads();

        // ---- S^T = K (Q*scale)^T : 4 tiles of 16k x 16q; lane: q=lr, k=t*16+lg*4+r
        floatx4 s[4];
        #pragma unroll
        for (int t = 0; t < 4; ++t) {
            half8 bk0 = *(const half8*)&sK[buf][(t * 16 + lr) * LDK + lg * 8];
            half8 bk1 = *(const half8*)&sK[buf][(t * 16 + lr) * LDK + 32 + lg * 8];
            floatx4 z = (floatx4){0.f, 0.f, 0.f, 0.f};
            z = __builtin_amdgcn_mfma_f32_16x16x32_f16(bk0, aq[0], z, 0, 0, 0);
            z = __builtin_amdgcn_mfma_f32_16x16x32_f16(bk1, aq[1], z, 0, 0, 0);
            s[t] = z;
        }

        // ---- online softmax: all state is per-q scalars (q = lr)
        float lm = s[0][0];
        #pragma unroll
        for (int t = 0; t < 4; ++t) {
            #pragma unroll
            for (int r = 0; r < 4; ++r) lm = fmaxf(lm, s[t][r]);
        }
        lm = fmaxf(lm, __shfl_xor(lm, 16, 64));
        lm = fmaxf(lm, __shfl_xor(lm, 32, 64));
        const float mn = fmaxf(m_run, lm);
        const float f  = __expf(m_run - mn);
        m_run = mn;
        #pragma unroll
        for (int t = 0; t < 4; ++t) {
            #pragma unroll
            for (int r = 0; r < 4; ++r) s[t][r] = __expf(s[t][r] - mn);
        }
        float ls = 0.f;
        #pragma unroll
        for (int t = 0; t < 4; ++t)
            ls += (s[t][0] + s[t][1]) + (s[t][2] + s[t][3]);
        ls += __shfl_xor(ls, 16, 64);
        ls += __shfl_xor(ls, 32, 64);
        l_run = l_run * f + ls;
        #pragma unroll
        for (int dt = 0; dt < 4; ++dt) {
            #pragma unroll
            for (int r = 0; r < 4; ++r) accT[dt][r] *= f;
        }

        // ---- P^T C-layout == B-layout of 16x16x16f16: pure in-lane f32->f16
        half4 pb[4];
        #pragma unroll
        for (int t = 0; t < 4; ++t) {
            half4 w = { (_Float16)s[t][0], (_Float16)s[t][1],
                        (_Float16)s[t][2], (_Float16)s[t][3] };
            pb[t] = w;
        }

        // ---- O^T += V^T P^T : A = V^T frags (b64 reads), B = pb
        #pragma unroll
        for (int dt = 0; dt < 4; ++dt) {
            #pragma unroll
            for (int t = 0; t < 4; ++t) {
                half4 va = *(const half4*)&sVT[buf][(dt * 16 + lr) * LDV + t * 16 + lg * 4];
                accT[dt] = __builtin_amdgcn_mfma_f32_16x16x16f16(va, pb[t], accT[dt], 0, 0, 0);
            }
        }
    }

    // ---- epilogue: O^T layout row=d_local, col=q -> contiguous float4 per lane
    const float inv = 1.0f / l_run;
    float* op = O + ((size_t)b * NSEQ + qrow0 + lr) * NDIM + h * DH;
    #pragma unroll
    for (int dt = 0; dt < 4; ++dt) {
        floatx4 o;
        #pragma unroll
        for (int r = 0; r < 4; ++r) o[r] = accT[dt][r] * inv;
        *(floatx4*)(op + dt * 16 + lg * 4) = o;
    }
}

extern "C" void kernel_launch(void* const* d_in, const int* in_sizes, int n_in,
                              void* d_out, int out_size, void* d_ws, size_t ws_size,
                              hipStream_t stream) {
    const float* Q = (const float*)d_in[0];
    const float* K = (const float*)d_in[1];
    const float* V = (const float*)d_in[2];
    float* O = (float*)d_out;
    dim3 grid(4 * 8 * (NSEQ / QB));   // 1024 = 256 CU x 4 blocks
    dim3 block(256);
    hipLaunchKernelGGL(mha_fwd, grid, block, 0, stream, Q, K, V, O);
}

// Round 3
// 95.341 us; speedup vs baseline: 1.4561x; 1.0711x over previous
//
#include <hip/hip_runtime.h>

typedef _Float16 half4 __attribute__((ext_vector_type(4)));
typedef _Float16 half8 __attribute__((ext_vector_type(8)));
typedef float floatx4 __attribute__((ext_vector_type(4)));

constexpr int NSEQ = 2048;
constexpr int NDIM = 512;
constexpr int DH   = 64;
constexpr float SCALE = 0.125f;                         // (512/8)^-0.5
constexpr float SCALE_L2E = 0.125f * 1.44269504088896340736f;  // fold log2(e): use exp2

#define GLOAD16(g, l) __builtin_amdgcn_global_load_lds( \
    (const __attribute__((address_space(1))) void*)(g), \
    (__attribute__((address_space(3))) void*)(l), 16, 0, 0)

// ================= prepass: K -> fp16 swizzled tiles, V -> fp16 transposed swizzled tiles ===========
// Tile image (8192 B) = linear LDS image: byte i: row=i>>7, bytecol=(i&127)^((row&7)<<4).
// K tile: row = k-row (0..63), col = d (0..63).  V^T tile: row = d, col = k-row.
__global__ __launch_bounds__(256) void mha_prep(const float* __restrict__ K,
                                                const float* __restrict__ V,
                                                _Float16* __restrict__ Kh,
                                                _Float16* __restrict__ VTh)
{
    const int bid = blockIdx.x;          // 0..2047 : [isV][bh][kt]
    const int isV = bid >> 10;
    const int t   = bid & 1023;
    const int kt  = t & 31, bh = t >> 5;
    const int h = bh & 7, b = bh >> 3;
    const int n0 = kt * 64;
    _Float16* dst = (isV ? VTh : Kh) + ((size_t)bh * 32 + kt) * 4096;
    const int tid = threadIdx.x;
    #pragma unroll
    for (int u = 0; u < 2; ++u) {
        const int c   = tid * 2 + u;               // 16B chunk 0..511
        const int row = c >> 3;
        const int bc  = ((c & 7) * 16) ^ ((row & 7) << 4);
        const int e0  = bc >> 1;                   // 8 consecutive logical cols
        half8 w;
        if (!isV) {
            const float* src = K + ((size_t)b * NSEQ + n0 + row) * NDIM + h * DH + e0;
            floatx4 x0 = *(const floatx4*)src;
            floatx4 x1 = *(const floatx4*)(src + 4);
            #pragma unroll
            for (int j = 0; j < 4; ++j) { w[j] = (_Float16)x0[j]; w[4 + j] = (_Float16)x1[j]; }
        } else {
            const float* src = V + ((size_t)b * NSEQ + n0 + e0) * NDIM + h * DH + row;
            #pragma unroll
            for (int j = 0; j < 8; ++j) w[j] = (_Float16)src[(size_t)j * NDIM];
        }
        *(half8*)(dst + (size_t)c * 8) = w;
    }
}

// ================= main: flash attention, 32 q-rows/wave, QB=128 =================
constexpr int QB3 = 128;
constexpr int KB  = 64;
constexpr int NT  = NSEQ / KB;

__launch_bounds__(256, 2)
__global__ void mha_fwd3(const float* __restrict__ Q,
                         const _Float16* __restrict__ Kh,
                         const _Float16* __restrict__ VTh,
                         float* __restrict__ O)
{
    __shared__ __align__(16) _Float16 sK[2][4096];    // 8 KB / buf, swizzled image
    __shared__ __align__(16) _Float16 sVT[2][4096];

    const int tid = threadIdx.x, wave = tid >> 6, lane = tid & 63;
    const int lr = lane & 15, lg = lane >> 4;

    // XCD swizzle: all 16 q-tiles of a (b,h) share bid%8 -> same XCD L2
    const int bid = blockIdx.x;                       // 512 blocks
    const int bh  = (bid & 7) + 8 * ((bid >> 3) >> 4);
    const int qt  = (bid >> 3) & 15;
    const int h = bh & 7, b = bh >> 3;
    const int qrow0 = qt * QB3 + wave * 32;

    // ---- Q fragments: 2 qsets x 2 k-chunks (B-layout: col=q=lr, k=lg*8+j), scale*log2e folded
    half8 aq[2][2];
    #pragma unroll
    for (int qs = 0; qs < 2; ++qs) {
        const float* qp = Q + ((size_t)b * NSEQ + qrow0 + qs * 16 + lr) * NDIM + h * DH;
        #pragma unroll
        for (int c = 0; c < 2; ++c) {
            floatx4 x0 = *(const floatx4*)(qp + c * 32 + lg * 8);
            floatx4 x1 = *(const floatx4*)(qp + c * 32 + lg * 8 + 4);
            #pragma unroll
            for (int j = 0; j < 4; ++j) {
                aq[qs][c][j]     = (_Float16)(x0[j] * SCALE_L2E);
                aq[qs][c][4 + j] = (_Float16)(x1[j] * SCALE_L2E);
            }
        }
    }

    const char* ktiles = (const char*)(Kh + (size_t)bh * 32 * 4096);
    const char* vtiles = (const char*)(VTh + (size_t)bh * 32 * 4096);

    // per-lane swizzled LDS read offsets
    const int sw  = (lr & 7) << 4;
    const int kb0 = lr * 128 + ((lg * 16) ^ sw);
    const int kb1 = lr * 128 + ((64 + lg * 16) ^ sw);

    floatx4 accT[4][2];
    #pragma unroll
    for (int dt = 0; dt < 4; ++dt)
        #pragma unroll
        for (int qs = 0; qs < 2; ++qs) accT[dt][qs] = (floatx4){0.f, 0.f, 0.f, 0.f};
    float m_run[2] = {-1e30f, -1e30f}, l_run[2] = {0.f, 0.f};

    auto ISSUE = [&](int kt, int buf) {
        const char* kb = ktiles + (size_t)kt * 8192 + wave * 2048 + lane * 16;
        const char* vb = vtiles + (size_t)kt * 8192 + wave * 2048 + lane * 16;
        char* sk = ((char*)&sK[buf][0]) + wave * 2048;
        char* sv = ((char*)&sVT[buf][0]) + wave * 2048;
        GLOAD16(kb, sk);
        GLOAD16(kb + 1024, sk + 1024);
        GLOAD16(vb, sv);
        GLOAD16(vb + 1024, sv + 1024);
    };

    ISSUE(0, 0);
    for (int kt = 0; kt < NT; ++kt) {
        const int buf = kt & 1;
        asm volatile("s_waitcnt vmcnt(0)" ::: "memory");
        __builtin_amdgcn_s_barrier();
        asm volatile("" ::: "memory");
        if (kt + 1 < NT) ISSUE(kt + 1, buf ^ 1);

        const char* skb = (const char*)&sK[buf][0];
        const char* svb = (const char*)&sVT[buf][0];

        // ---- S^T = K (Q*scale)^T : lane q=lr (per qset), k = t*16 + lg*4 + r
        floatx4 s[4][2];
        #pragma unroll
        for (int t = 0; t < 4; ++t) {
            half8 k0 = *(const half8*)(skb + t * 2048 + kb0);
            half8 k1 = *(const half8*)(skb + t * 2048 + kb1);
            #pragma unroll
            for (int qs = 0; qs < 2; ++qs) {
                floatx4 z = (floatx4){0.f, 0.f, 0.f, 0.f};
                z = __builtin_amdgcn_mfma_f32_16x16x32_f16(k0, aq[qs][0], z, 0, 0, 0);
                z = __builtin_amdgcn_mfma_f32_16x16x32_f16(k1, aq[qs][1], z, 0, 0, 0);
                s[t][qs] = z;
            }
        }

        // ---- online softmax (log2 domain), per-q scalars
        float lm[2];
        #pragma unroll
        for (int qs = 0; qs < 2; ++qs) {
            float m = s[0][qs][0];
            #pragma unroll
            for (int t = 0; t < 4; ++t)
                #pragma unroll
                for (int r = 0; r < 4; ++r) m = fmaxf(m, s[t][qs][r]);
            m = fmaxf(m, __shfl_xor(m, 16, 64));
            m = fmaxf(m, __shfl_xor(m, 32, 64));
            lm[qs] = m;
        }
        const bool need = (lm[0] > m_run[0]) | (lm[1] > m_run[1]);
        if (__any(need)) {
            #pragma unroll
            for (int qs = 0; qs < 2; ++qs) {
                const float mn = fmaxf(m_run[qs], lm[qs]);
                const float f  = exp2f(m_run[qs] - mn);
                m_run[qs] = mn;
                l_run[qs] *= f;
                #pragma unroll
                for (int dt = 0; dt < 4; ++dt)
                    #pragma unroll
                    for (int r = 0; r < 4; ++r) accT[dt][qs][r] *= f;
            }
        }

        half4 pb[4][2];
        #pragma unroll
        for (int qs = 0; qs < 2; ++qs) {
            float ls = 0.f;
            #pragma unroll
            for (int t = 0; t < 4; ++t) {
                floatx4 e;
                #pragma unroll
                for (int r = 0; r < 4; ++r) e[r] = exp2f(s[t][qs][r] - m_run[qs]);
                ls += (e[0] + e[1]) + (e[2] + e[3]);
                half4 w = { (_Float16)e[0], (_Float16)e[1], (_Float16)e[2], (_Float16)e[3] };
                pb[t][qs] = w;
            }
            ls += __shfl_xor(ls, 16, 64);
            ls += __shfl_xor(ls, 32, 64);
            l_run[qs] += ls;
        }

        // ---- O^T += V^T P^T (va shared across qsets)
        #pragma unroll
        for (int dt = 0; dt < 4; ++dt) {
            #pragma unroll
            for (int t = 0; t < 4; ++t) {
                half4 va = *(const half4*)(svb + dt * 2048 + lr * 128 + (((t * 32) + (lg * 8)) ^ sw));
                #pragma unroll
                for (int qs = 0; qs < 2; ++qs)
                    accT[dt][qs] = __builtin_amdgcn_mfma_f32_16x16x16f16(va, pb[t][qs], accT[dt][qs], 0, 0, 0);
            }
        }
    }

    // ---- epilogue
    #pragma unroll
    for (int qs = 0; qs < 2; ++qs) {
        const float inv = 1.0f / l_run[qs];
        float* op = O + ((size_t)b * NSEQ + qrow0 + qs * 16 + lr) * NDIM + h * DH;
        #pragma unroll
        for (int dt = 0; dt < 4; ++dt) {
            floatx4 o;
            #pragma unroll
            for (int r = 0; r < 4; ++r) o[r] = accT[dt][qs][r] * inv;
            *(floatx4*)(op + dt * 16 + lg * 4) = o;
        }
    }
}

// ================= fallback (v2, no workspace needed) =================
constexpr int QB2 = 64;
constexpr int LDK = DH + 8;
constexpr int LDV = KB + 8;

__launch_bounds__(256, 4)
__global__ void mha_fwd2(const float* __restrict__ Q,
                         const float* __restrict__ K,
                         const float* __restrict__ V,
                         float* __restrict__ O)
{
    __shared__ _Float16 sK[2][KB * LDK];
    __shared__ _Float16 sVT[2][DH * LDV];

    const int tid = threadIdx.x, wave = tid >> 6, lane = tid & 63;
    const int lr = lane & 15, lg = lane >> 4;
    const int bid = blockIdx.x;
    const int qt = bid & 31, bh = bid >> 5;
    const int h = bh & 7, b = bh >> 3;
    const int qrow0 = qt * QB2 + wave * 16;

    half8 aq[2];
    {
        const float* qp = Q + ((size_t)b * NSEQ + qrow0 + lr) * NDIM + h * DH;
        #pragma unroll
        for (int c = 0; c < 2; ++c) {
            floatx4 x0 = *(const floatx4*)(qp + c * 32 + lg * 8);
            floatx4 x1 = *(const floatx4*)(qp + c * 32 + lg * 8 + 4);
            #pragma unroll
            for (int j = 0; j < 4; ++j) {
                aq[c][j] = (_Float16)(x0[j] * SCALE);
                aq[c][4 + j] = (_Float16)(x1[j] * SCALE);
            }
        }
    }
    const int jk = tid >> 2, ck = (tid & 3) * 16;
    const int jv = (tid & 15) * 4, cv = (tid >> 4) * 4;
    const float* kbase = K + (size_t)b * NSEQ * NDIM + h * DH;
    const float* vbase = V + (size_t)b * NSEQ * NDIM + h * DH;

    floatx4 rk[4], rv[4];
    auto LOAD = [&](int kt) {
        const float* ks = kbase + (size_t)(kt * KB + jk) * NDIM + ck;
        #pragma unroll
        for (int q4 = 0; q4 < 4; ++q4) rk[q4] = *(const floatx4*)(ks + q4 * 4);
        const float* vs = vbase + (size_t)(kt * KB + jv) * NDIM + cv;
        #pragma unroll
        for (int i = 0; i < 4; ++i) rv[i] = *(const floatx4*)(vs + (size_t)i * NDIM);
    };
    auto WRITE = [&](int buf) {
        #pragma unroll
        for (int q4 = 0; q4 < 4; ++q4) {
            half4 w = { (_Float16)rk[q4][0], (_Float16)rk[q4][1],
                        (_Float16)rk[q4][2], (_Float16)rk[q4][3] };
            *(half4*)&sK[buf][jk * LDK + ck + q4 * 4] = w;
        }
        #pragma unroll
        for (int cc = 0; cc < 4; ++cc) {
            half4 w = { (_Float16)rv[0][cc], (_Float16)rv[1][cc],
                        (_Float16)rv[2][cc], (_Float16)rv[3][cc] };
            *(half4*)&sVT[buf][(cv + cc) * LDV + jv] = w;
        }
    };

    floatx4 accT[4];
    #pragma unroll
    for (int t = 0; t < 4; ++t) accT[t] = (floatx4){0.f, 0.f, 0.f, 0.f};
    float m_run = -1e30f, l_run = 0.f;

    LOAD(0);
    #pragma unroll 2
    for (int kt = 0; kt < NT; ++kt) {
        const int buf = kt & 1;
        WRITE(buf);
        if (kt + 1 < NT) LOAD(kt + 1);
        __syncthreads();

        floatx4 s[4];
        #pragma unroll
        for (int t = 0; t < 4; ++t) {
            half8 bk0 = *(const half8*)&sK[buf][(t * 16 + lr) * LDK + lg * 8];
            half8 bk1 = *(const half8*)&sK[buf][(t * 16 + lr) * LDK + 32 + lg * 8];
            floatx4 z = (floatx4){0.f, 0.f, 0.f, 0.f};
            z = __builtin_amdgcn_mfma_f32_16x16x32_f16(bk0, aq[0], z, 0, 0, 0);
            z = __builtin_amdgcn_mfma_f32_16x16x32_f16(bk1, aq[1], z, 0, 0, 0);
            s[t] = z;
        }
        float lm = s[0][0];
        #pragma unroll
        for (int t = 0; t < 4; ++t)
            #pragma unroll
            for (int r = 0; r < 4; ++r) lm = fmaxf(lm, s[t][r]);
        lm = fmaxf(lm, __shfl_xor(lm, 16, 64));
        lm = fmaxf(lm, __shfl_xor(lm, 32, 64));
        const float mn = fmaxf(m_run, lm);
        const float f = __expf(m_run - mn);
        m_run = mn;
        #pragma unroll
        for (int t = 0; t < 4; ++t)
            #pragma unroll
            for (int r = 0; r < 4; ++r) s[t][r] = __expf(s[t][r] - mn);
        float ls = 0.f;
        #pragma unroll
        for (int t = 0; t < 4; ++t) ls += (s[t][0] + s[t][1]) + (s[t][2] + s[t][3]);
        ls += __shfl_xor(ls, 16, 64);
        ls += __shfl_xor(ls, 32, 64);
        l_run = l_run * f + ls;
        #pragma unroll
        for (int dt = 0; dt < 4; ++dt)
            #pragma unroll
            for (int r = 0; r < 4; ++r) accT[dt][r] *= f;

        half4 pb[4];
        #pragma unroll
        for (int t = 0; t < 4; ++t) {
            half4 w = { (_Float16)s[t][0], (_Float16)s[t][1],
                        (_Float16)s[t][2], (_Float16)s[t][3] };
            pb[t] = w;
        }
        #pragma unroll
        for (int dt = 0; dt < 4; ++dt) {
            #pragma unroll
            for (int t = 0; t < 4; ++t) {
                half4 va = *(const half4*)&sVT[buf][(dt * 16 + lr) * LDV + t * 16 + lg * 4];
                accT[dt] = __builtin_amdgcn_mfma_f32_16x16x16f16(va, pb[t], accT[dt], 0, 0, 0);
            }
        }
    }
    const float inv = 1.0f / l_run;
    float* op = O + ((size_t)b * NSEQ + qrow0 + lr) * NDIM + h * DH;
    #pragma unroll
    for (int dt = 0; dt < 4; ++dt) {
        floatx4 o;
        #pragma unroll
        for (int r = 0; r < 4; ++r) o[r] = accT[dt][r] * inv;
        *(floatx4*)(op + dt * 16 + lg * 4) = o;
    }
}

extern "C" void kernel_launch(void* const* d_in, const int* in_sizes, int n_in,
                              void* d_out, int out_size, void* d_ws, size_t ws_size,
                              hipStream_t stream) {
    const float* Q = (const float*)d_in[0];
    const float* K = (const float*)d_in[1];
    const float* V = (const float*)d_in[2];
    float* O = (float*)d_out;

    const size_t need = (size_t)2 * 4 * 8 * 32 * 4096 * sizeof(_Float16);  // 16 MB
    if (ws_size >= need) {
        _Float16* Kh  = (_Float16*)d_ws;
        _Float16* VTh = Kh + (size_t)4 * 8 * 32 * 4096;
        hipLaunchKernelGGL(mha_prep, dim3(2048), dim3(256), 0, stream, K, V, Kh, VTh);
        hipLaunchKernelGGL(mha_fwd3, dim3(512), dim3(256), 0, stream, Q, Kh, VTh, O);
    } else {
        hipLaunchKernelGGL(mha_fwd2, dim3(1024), dim3(256), 0, stream, Q, K, V, O);
    }
}